// Round 2
// baseline (282.258 us; speedup 1.0000x reference)
//
#include <hip/hip_runtime.h>
#include <cmath>

// Sampler: B=256 rows, V=128000 vocab.
// out[0..255]           = tokens (as float values; harness reads concat buffer)
// out[256 .. 256+B*V)   = final probs (min-p renormalized), mostly zeros
//
// Single fused kernel, one block per row:
//   pass 0: stream logits once — zero-write output row, running row-max,
//           gather candidates (l >= 6.0; exp count ~173 for N(0,2) logits)
//   (rare)  bisection retry if count outside [64, CAP]
//   wave 0: register-resident top-64 extraction (no sort, no barriers),
//           exact top-k/top-p/min-p/inverse-CDF math with shuffle reductions.
// The softmax denominator Z cancels in every renorm -> never computed.
// Only the top-63 tokens can survive top-k, so top-64 candidates suffice.

constexpr int BB   = 256;
constexpr int VV   = 128000;
constexpr int CAP  = 512;       // candidate capacity (26 sigma above mean 173)
constexpr int NVEC = VV / 4;
constexpr int IPL  = CAP / 64;  // items per lane in extraction (8)

__global__ __launch_bounds__(1024) void k_fused(
    const float* __restrict__ logits, const float* __restrict__ temps,
    const int* __restrict__ topks, const float* __restrict__ topps,
    const float* __restrict__ minps, const float* __restrict__ noise,
    float* __restrict__ out) {
  const int row = blockIdx.x;
  const int tid = threadIdx.x;
  const float* lrow = logits + (size_t)row * VV;
  float* orow = out + BB + (size_t)row * VV;

  __shared__ float cl[CAP];
  __shared__ int   ci[CAP];
  __shared__ int   s_cnt;
  __shared__ float s_t, s_lo, s_hi, s_max;
  __shared__ float wmax[16];

  if (tid == 0) s_cnt = 0;
  __syncthreads();

  const float4* lp4 = reinterpret_cast<const float4*>(lrow);
  float4* op4 = reinterpret_cast<float4*>(orow);
  const float4 z4 = make_float4(0.f, 0.f, 0.f, 0.f);
  const float T0 = 6.0f;

  // ---- pass 0: stream read + zero write + max + gather ----
  float m = -INFINITY;
  for (int j = tid; j < NVEC; j += 1024) {
    const float4 v = lp4[j];
    op4[j] = z4;
    m = fmaxf(fmaxf(fmaxf(v.x, v.y), fmaxf(v.z, v.w)), m);
    const int base = j << 2;
    if (v.x >= T0) { int p = atomicAdd(&s_cnt, 1); if (p < CAP) { cl[p] = v.x; ci[p] = base;     } }
    if (v.y >= T0) { int p = atomicAdd(&s_cnt, 1); if (p < CAP) { cl[p] = v.y; ci[p] = base + 1; } }
    if (v.z >= T0) { int p = atomicAdd(&s_cnt, 1); if (p < CAP) { cl[p] = v.z; ci[p] = base + 2; } }
    if (v.w >= T0) { int p = atomicAdd(&s_cnt, 1); if (p < CAP) { cl[p] = v.w; ci[p] = base + 3; } }
  }
  for (int o = 32; o > 0; o >>= 1) m = fmaxf(m, __shfl_xor(m, o, 64));
  if ((tid & 63) == 0) wmax[tid >> 6] = m;
  __syncthreads();                       // s_cnt, cl/ci, wmax all visible
  if (tid == 0) {
    float mm = wmax[0];
    for (int i = 1; i < 16; ++i) mm = fmaxf(mm, wmax[i]);
    s_max = mm;
    s_lo = mm - 40.0f;                   // known "too many" side
    s_hi = mm + 1.0f;                    // known "too few" side
  }
  __syncthreads();
  int cnt = s_cnt;

  // ---- rare bisection retry (L3-warm re-read); uniform control flow ----
  float tcur = T0;
  for (int it = 0; it < 24 && (cnt < 64 || cnt > CAP); ++it) {
    if (tid == 0) {
      if (cnt > CAP) s_lo = tcur; else s_hi = tcur;
      s_t = 0.5f * (s_lo + s_hi);
      s_cnt = 0;
    }
    __syncthreads();
    tcur = s_t;
    for (int j = tid; j < NVEC; j += 1024) {
      const float4 v = lp4[j];
      const int base = j << 2;
      if (v.x >= tcur) { int p = atomicAdd(&s_cnt, 1); if (p < CAP) { cl[p] = v.x; ci[p] = base;     } }
      if (v.y >= tcur) { int p = atomicAdd(&s_cnt, 1); if (p < CAP) { cl[p] = v.y; ci[p] = base + 1; } }
      if (v.z >= tcur) { int p = atomicAdd(&s_cnt, 1); if (p < CAP) { cl[p] = v.z; ci[p] = base + 2; } }
      if (v.w >= tcur) { int p = atomicAdd(&s_cnt, 1); if (p < CAP) { cl[p] = v.w; ci[p] = base + 3; } }
    }
    __syncthreads();
    cnt = s_cnt;
  }
  const int n = min(cnt, CAP);

  // ---- wave 0: top-64 extraction + exact selection math ----
  if (tid < 64) {
    const int lane = tid;
    // candidates into registers, 8 per lane, statically indexed
    float rv[IPL]; int rix[IPL];
#pragma unroll
    for (int q = 0; q < IPL; ++q) {
      const int idx = lane + (q << 6);
      const bool ok = idx < n;
      rv[q]  = ok ? cl[idx] : -INFINITY;
      rix[q] = ok ? ci[idx] : 0x7fffffff;
    }
    const int n64 = min(n, 64);
    float lv = 0.0f; int iv = 0x7fffffff;
    for (int r = 0; r < n64; ++r) {      // uniform trip count
      float bv = rv[0]; int bi = rix[0];
#pragma unroll
      for (int q = 1; q < IPL; ++q) if (rv[q] > bv) { bv = rv[q]; bi = rix[q]; }
      for (int o = 32; o > 0; o >>= 1) {
        const float ov = __shfl_xor(bv, o, 64);
        const int   oi = __shfl_xor(bi, o, 64);
        if (ov > bv || (ov == bv && oi < bi)) { bv = ov; bi = oi; }
      }
#pragma unroll
      for (int q = 0; q < IPL; ++q) if (rix[q] == bi) { rv[q] = -INFINITY; rix[q] = 0x7fffffff; }
      if (lane == r) { lv = bv; iv = bi; }   // lane r owns r-th largest
    }

    const float Tv = temps[row];
    const float Mx = s_max / Tv;         // == max(l/T): division by T>0 is monotone
    const bool valid = lane < n64;
    const float p = valid ? expf(lv / Tv - Mx) : 0.0f;   // Z cancels everywhere

    int k = topks[row];
    k = max(1, min(k, n64));
    const float kth = __shfl(p, k - 1, 64);
    const bool keepA = valid && (p >= kth);              // top-k (with ties)
    float S1 = keepA ? p : 0.0f;
    for (int o = 32; o > 0; o >>= 1) S1 += __shfl_xor(S1, o, 64);
    const float q = keepA ? (p / S1) : 0.0f;

    // top-p: keep while exclusive-cumsum < top_p; then q >= (min kept q)
    float cs = q;
    for (int o = 1; o < 64; o <<= 1) { const float v = __shfl_up(cs, o, 64); if (lane >= o) cs += v; }
    const float lhs = cs - q;                            // mimics (csum - sorted)
    const bool keepBp = keepA && (lhs < topps[row]);
    float thr = keepBp ? q : INFINITY;
    for (int o = 32; o > 0; o >>= 1) thr = fminf(thr, __shfl_xor(thr, o, 64));
    const bool keepB = keepA && (q >= thr);
    float S2 = keepB ? q : 0.0f;
    for (int o = 32; o > 0; o >>= 1) S2 += __shfl_xor(S2, o, 64);
    const float r2 = keepB ? (q / S2) : 0.0f;

    // min-p
    const float r0 = __shfl(r2, 0, 64);                  // lane 0 = max prob
    const bool keepC = keepB && (r2 >= minps[row] * r0);
    float S3 = keepC ? r2 : 0.0f;
    for (int o = 32; o > 0; o >>= 1) S3 += __shfl_xor(S3, o, 64);
    const float f = keepC ? (r2 / S3) : 0.0f;            // final probs

    // inverse-CDF sample in token-index order (zeros are fp no-ops)
    float cum = 0.0f, tot = 0.0f;
    for (int i2 = 0; i2 < 64; ++i2) {
      const float fi = __shfl(f, i2, 64);
      const int   ii = __shfl(iv, i2, 64);
      tot += fi;
      if (ii <= iv) cum += fi;           // same add sequence as tot at max-idx lane
    }
    const float target = noise[row] * tot;
    int tok = 0;                          // target<=0 -> argmax(cdf>=0) = 0
    if (target > 0.0f) {
      int cand = (keepC && cum >= target) ? iv : 0x7fffffff;
      for (int o = 32; o > 0; o >>= 1) cand = min(cand, __shfl_xor(cand, o, 64));
      if (cand == 0x7fffffff) {          // fp safety net
        int mi = keepC ? iv : -1;
        for (int o = 32; o > 0; o >>= 1) mi = max(mi, __shfl_xor(mi, o, 64));
        cand = (mi < 0) ? 0 : mi;
      }
      tok = cand;
    }

    if (keepC) orow[iv] = f;             // scatter (zero-writes drained at barriers)
    if (lane == 0) out[row] = (float)tok;
  }
}

extern "C" void kernel_launch(void* const* d_in, const int* in_sizes, int n_in,
                              void* d_out, int out_size, void* d_ws, size_t ws_size,
                              hipStream_t stream) {
  const float* logits = (const float*)d_in[0];
  const float* temps  = (const float*)d_in[1];
  const int*   topks  = (const int*)d_in[2];
  const float* topps  = (const float*)d_in[3];
  const float* minps  = (const float*)d_in[4];
  const float* noise  = (const float*)d_in[5];
  float* out = (float*)d_out;

  k_fused<<<BB, 1024, 0, stream>>>(logits, temps, topks, topps, minps, noise, out);
}